// Round 4
// baseline (640.058 us; speedup 1.0000x reference)
//
#include <hip/hip_runtime.h>

// dims
#define Bn 4
#define Ln 256
#define Hn 768
#define Tn 16

// ---------------- K1: LayerNorm over H (fp32 in/out) ----------------
__global__ __launch_bounds__(256) void k_ln0(const float* __restrict__ x,
                                             const float* __restrict__ g,
                                             const float* __restrict__ be,
                                             float* __restrict__ out) {
    int row = blockIdx.x, tid = threadIdx.x;
    const float* xr = x + (size_t)row * Hn;
    float v0 = xr[tid], v1 = xr[tid + 256], v2 = xr[tid + 512];
    float s = v0 + v1 + v2;
    float q = v0 * v0 + v1 * v1 + v2 * v2;
    __shared__ float sm[4], qm[4];
    for (int o = 32; o > 0; o >>= 1) { s += __shfl_down(s, o); q += __shfl_down(q, o); }
    if ((tid & 63) == 0) { sm[tid >> 6] = s; qm[tid >> 6] = q; }
    __syncthreads();
    float S = sm[0] + sm[1] + sm[2] + sm[3];
    float Q = qm[0] + qm[1] + qm[2] + qm[3];
    float mean = S * (1.f / 768.f);
    float rstd = rsqrtf(Q * (1.f / 768.f) - mean * mean + 1e-5f);
    float* o0 = out + (size_t)row * Hn;
    o0[tid]       = (v0 - mean) * rstd * g[tid]       + be[tid];
    o0[tid + 256] = (v1 - mean) * rstd * g[tid + 256] + be[tid + 256];
    o0[tid + 512] = (v2 - mean) * rstd * g[tid + 512] + be[tid + 512];
}

// ---------------- K3: node features nf = concat(asp,opi,sv) @ W_tp + b_tp --------
__global__ __launch_bounds__(256) void k_nf(const float* __restrict__ emb,
                                            const int* __restrict__ ast_, const int* __restrict__ aed_,
                                            const int* __restrict__ ost_, const int* __restrict__ oed_,
                                            const int* __restrict__ sid_,
                                            const float* __restrict__ Wtp,
                                            const float* __restrict__ btp,
                                            float* __restrict__ nf) {
    int n = blockIdx.x;                 // b*16 + t
    int b = n >> 4;
    int tid = threadIdx.x;
    __shared__ float xv[1539];
    int ast = ast_[n], aed = aed_[n], ost = ost_[n], oed = oed_[n], sid = sid_[n];
    float ai = 1.f / (float)(aed - ast + 1);
    float oi = 1.f / (float)(oed - ost + 1);
    const float* eb = emb + (size_t)b * Ln * Hn;
    for (int h = tid; h < 768; h += 256) {
        float sa = 0.f;
        for (int l = ast; l <= aed; ++l) sa += eb[l * Hn + h];
        xv[h] = sa * ai;
        float so = 0.f;
        for (int l = ost; l <= oed; ++l) so += eb[l * Hn + h];
        xv[768 + h] = so * oi;
    }
    if (tid < 3) xv[1536 + tid] = (sid - 2 == tid) ? 1.f : 0.f;
    __syncthreads();
    float a0 = btp[tid], a1 = btp[tid + 256], a2 = btp[tid + 512];
#pragma unroll 4
    for (int r = 0; r < 1539; ++r) {
        float xr = xv[r];
        const float* wr = Wtp + (size_t)r * 768;
        a0 = fmaf(xr, wr[tid], a0);
        a1 = fmaf(xr, wr[tid + 256], a1);
        a2 = fmaf(xr, wr[tid + 512], a2);
    }
    float* o = nf + (size_t)n * Hn;
    o[tid] = a0; o[tid + 256] = a1; o[tid + 512] = a2;
}

// ---------------- K4: graph attention (small) ----------------
__global__ __launch_bounds__(256) void k_graph(const float* __restrict__ nf,
                                               const int* __restrict__ ast_, const int* __restrict__ aed_,
                                               const int* __restrict__ ost_, const int* __restrict__ oed_,
                                               const float* __restrict__ E,
                                               const float* __restrict__ Wat,
                                               const float* __restrict__ bat,
                                               float* __restrict__ w_out, float* __restrict__ ae_out,
                                               int* __restrict__ hasin, float* __restrict__ hasedge) {
    int b = blockIdx.x, tid = threadIdx.x;
    __shared__ int ast[16], aed[16], ost[16], oed[16];
    __shared__ float red[256];
    __shared__ float nrm[16], p[16], q[16], rr[2];
    __shared__ unsigned m0b[16], m1b[16];
    if (tid < 16) {
        int n = b * 16 + tid;
        ast[tid] = ast_[n]; aed[tid] = aed_[n]; ost[tid] = ost_[n]; oed[tid] = oed_[n];
        m0b[tid] = 0u; m1b[tid] = 0u;
    }
    int t = tid >> 4, lane = tid & 15;
    const float* nt = nf + (size_t)(b * 16 + t) * Hn;
    float ss = 0.f, pp = 0.f, qq = 0.f;
    for (int h = lane; h < 768; h += 16) {
        float v = nt[h];
        ss = fmaf(v, v, ss);
        float lr = v > 0.f ? v : 0.2f * v;
        pp = fmaf(lr, Wat[h], pp);
        qq = fmaf(lr, Wat[768 + h], qq);
    }
    red[tid] = ss; __syncthreads();
    if (tid < 16) { float s = 0.f; for (int k2 = 0; k2 < 16; ++k2) s += red[tid * 16 + k2]; nrm[tid] = sqrtf(s); }
    __syncthreads();
    red[tid] = pp; __syncthreads();
    if (tid < 16) { float s = 0.f; for (int k2 = 0; k2 < 16; ++k2) s += red[tid * 16 + k2]; p[tid] = s; }
    __syncthreads();
    red[tid] = qq; __syncthreads();
    if (tid < 16) { float s = 0.f; for (int k2 = 0; k2 < 16; ++k2) s += red[tid * 16 + k2]; q[tid] = s; }
    __syncthreads();
    float rp = 0.f;
    if (tid < 32) {
        int e = tid >> 4;
        for (int h = lane; h < 768; h += 16) {
            float v = E[e * 768 + h];
            float lr = v > 0.f ? v : 0.2f * v;
            rp = fmaf(lr, Wat[1536 + h], rp);
        }
    }
    red[tid] = rp; __syncthreads();
    if (tid < 2) { float s = 0.f; for (int k2 = 0; k2 < 16; ++k2) s += red[tid * 16 + k2]; rr[tid] = s; }
    __syncthreads();
    // cosine sim, edge masks
    {
        int i = tid >> 4, j = tid & 15;
        const float* ni = nf + (size_t)(b * 16 + i) * Hn;
        const float* nj = nf + (size_t)(b * 16 + j) * Hn;
        float dot = 0.f;
        for (int h = 0; h < 768; ++h) dot = fmaf(ni[h], nj[h], dot);
        float sim = dot / (fmaxf(nrm[i], 1e-8f) * fmaxf(nrm[j], 1e-8f));
        bool ok = (sim > 0.f) && (i != j);
        if (ok && ast[i] == ast[j] && aed[i] == aed[j]) atomicOr(&m0b[i], 1u << j);
        if (ok && ost[i] == ost[j] && oed[i] == oed[j]) atomicOr(&m1b[i], 1u << j);
    }
    __syncthreads();
    if (tid < 16) {
        int tt = tid;
        float battn = bat[0];
        float sc[32];
        float mx = -3.4e38f;
        bool hi = false;
#pragma unroll
        for (int s = 0; s < 16; ++s) {
            bool e0 = (m0b[s] >> tt) & 1u;   // emask[t,s,0] = m0[s,t]
            bool e1 = (m1b[s] >> tt) & 1u;
            float base = p[tt] + q[s] + battn;
            float v0 = e0 ? (base + rr[0]) : -1e9f;
            float v1 = e1 ? (base + rr[1]) : -1e9f;
            sc[2 * s] = v0; sc[2 * s + 1] = v1;
            mx = fmaxf(mx, fmaxf(v0, v1));
            hi = hi || e0 || e1;
        }
        float sum = 0.f;
#pragma unroll
        for (int k2 = 0; k2 < 32; ++k2) { float e = expf(sc[k2] - mx); sc[k2] = e; sum += e; }
        float inv = 1.f / sum;
        float ae0 = 0.f, ae1 = 0.f;
#pragma unroll
        for (int s = 0; s < 16; ++s) {
            float w0 = sc[2 * s] * inv, w1 = sc[2 * s + 1] * inv;
            w_out[(size_t)(b * 16 + tt) * 16 + s] = w0 + w1;
            ae0 += w0; ae1 += w1;
        }
        ae_out[(b * 16 + tt) * 2 + 0] = ae0;
        ae_out[(b * 16 + tt) * 2 + 1] = ae1;
        hasin[b * 16 + tt] = hi ? 1 : 0;
        red[tid] = hi ? 1.f : 0.f;
    }
    __syncthreads();
    if (tid == 0) {
        float he = 0.f;
        for (int k2 = 0; k2 < 16; ++k2) he = fmaxf(he, red[k2]);
        hasedge[b] = he;
    }
}

// ---------------- K5: GAT update + scatter add into emb ----------------
__global__ __launch_bounds__(256) void k_upd(const float* __restrict__ nf,
                                             const float* __restrict__ w, const float* __restrict__ ae,
                                             const int* __restrict__ hasin, const float* __restrict__ hasedge,
                                             const int* __restrict__ ast_, const int* __restrict__ ost_,
                                             const float* __restrict__ E,
                                             const float* __restrict__ Wg,
                                             const float* __restrict__ bg,
                                             float* __restrict__ emb) {
    int n = blockIdx.x;            // b*16 + t
    int b = n >> 4;
    int tid = threadIdx.x;
    if (hasedge[b] == 0.f) return;
    int center = (ast_[n] + ost_[n]) >> 1;
    float* dst = emb + (size_t)(b * Ln + center) * Hn;
    if (hasin[n]) {
        __shared__ float agg[1536];
        const float* nfb = nf + (size_t)b * 16 * Hn;
        const float* wt = w + (size_t)n * 16;
        float ae0 = ae[n * 2], ae1 = ae[n * 2 + 1];
        for (int f = tid; f < 768; f += 256) {
            float s = 0.f;
#pragma unroll
            for (int s16 = 0; s16 < 16; ++s16) s = fmaf(wt[s16], nfb[s16 * Hn + f], s);
            agg[f] = s;
            agg[768 + f] = ae0 * E[f] + ae1 * E[768 + f];
        }
        __syncthreads();
        float a0 = bg[tid], a1 = bg[tid + 256], a2 = bg[tid + 512];
#pragma unroll 4
        for (int r = 0; r < 1536; ++r) {
            float xr = agg[r];
            const float* wr = Wg + (size_t)r * 768;
            a0 = fmaf(xr, wr[tid], a0);
            a1 = fmaf(xr, wr[tid + 256], a1);
            a2 = fmaf(xr, wr[tid + 512], a2);
        }
        atomicAdd(&dst[tid], fmaxf(a0, 0.f));
        atomicAdd(&dst[tid + 256], fmaxf(a1, 0.f));
        atomicAdd(&dst[tid + 512], fmaxf(a2, 0.f));
    } else {
        const float* nft = nf + (size_t)n * Hn;
        atomicAdd(&dst[tid], nft[tid]);
        atomicAdd(&dst[tid + 256], nft[tid + 256]);
        atomicAdd(&dst[tid + 512], nft[tid + 512]);
    }
}

// ---------------- K7: fp32 tiled GEMM  abm[1024][512] ----------------
// abm[m][n] = sum_k emb[m][k] * B[k][n],  B[k][n] = n<256 ? W1[k][n] : W1[768+k][n-256]
__global__ __launch_bounds__(256) void k_gemm32(const float* __restrict__ emb,
                                                const float* __restrict__ W1,
                                                float* __restrict__ abm) {
    __shared__ float At[32][33], Bt[32][33];
    int tid = threadIdx.x;
    int m0 = blockIdx.y * 32, n0 = blockIdx.x * 32;
    int tm = tid >> 3, tn4 = (tid & 7) * 4;
    float acc0 = 0.f, acc1 = 0.f, acc2 = 0.f, acc3 = 0.f;
    int lr = tid >> 3, lc = (tid & 7) * 4;
    for (int k0 = 0; k0 < 768; k0 += 32) {
        float4 av = *(const float4*)(emb + (size_t)(m0 + lr) * 768 + k0 + lc);
        At[lr][lc] = av.x; At[lr][lc + 1] = av.y; At[lr][lc + 2] = av.z; At[lr][lc + 3] = av.w;
        int gk = k0 + lr;
        int gn = n0 + lc;
        const float* src = (gn < 256) ? (W1 + (size_t)gk * 256 + gn)
                                      : (W1 + (size_t)(768 + gk) * 256 + (gn - 256));
        float4 bv = *(const float4*)src;
        Bt[lr][lc] = bv.x; Bt[lr][lc + 1] = bv.y; Bt[lr][lc + 2] = bv.z; Bt[lr][lc + 3] = bv.w;
        __syncthreads();
#pragma unroll
        for (int k = 0; k < 32; ++k) {
            float a = At[tm][k];
            acc0 = fmaf(a, Bt[k][tn4], acc0);
            acc1 = fmaf(a, Bt[k][tn4 + 1], acc1);
            acc2 = fmaf(a, Bt[k][tn4 + 2], acc2);
            acc3 = fmaf(a, Bt[k][tn4 + 3], acc3);
        }
        __syncthreads();
    }
    float* dst = abm + (size_t)(m0 + tm) * 512 + n0 + tn4;
    dst[0] = acc0; dst[1] = acc1; dst[2] = acc2; dst[3] = acc3;
}

// ---------------- K8: fused LN+GELU+proj over [B,L,L,L] — fp32 output ----------
__global__ __launch_bounds__(256) void k_hidden(const float* __restrict__ abm,
                                                const float* __restrict__ masks,
                                                const float* __restrict__ bl1,
                                                const float* __restrict__ g1,
                                                const float* __restrict__ b1,
                                                const float* __restrict__ Wc,
                                                const float* __restrict__ bc,
                                                const float* __restrict__ Wc1,
                                                const float* __restrict__ bc1,
                                                float* __restrict__ out) {
    __shared__ __align__(16) float As[32][260];
    __shared__ __align__(16) float Bs[16][260];
    __shared__ __align__(16) float g1s[256];
    __shared__ __align__(16) float b1s[256];
    __shared__ __align__(16) float wchf[256][8];
    __shared__ float bcs[8];
    int tid = threadIdx.x;
    int jt = blockIdx.x, it = blockIdx.y, b = blockIdx.z;
    const float* Ag = abm + (size_t)(b * 256 + it * 32) * 512;
    const float* Bg = abm + (size_t)(b * 256 + jt * 16) * 512 + 256;
#pragma unroll
    for (int u = 0; u < 32; ++u) {
        As[u][tid] = Ag[u * 512 + tid];
    }
#pragma unroll
    for (int u = 0; u < 16; ++u) {
        Bs[u][tid] = Bg[u * 512 + tid] + bl1[tid];
    }
    g1s[tid] = g1[tid];
    b1s[tid] = b1[tid];
    {
        int k = tid;
#pragma unroll
        for (int c = 0; c < 6; ++c) wchf[k][c] = Wc[k * 6 + c];
        wchf[k][6] = Wc1[k * 2];
        wchf[k][7] = Wc1[k * 2 + 1];
    }
    if (tid < 6) bcs[tid] = bc[tid];
    else if (tid < 8) bcs[tid] = bc1[tid - 6];
    __syncthreads();

    int i0 = (tid >> 4) * 2;
    int jl = tid & 15;
    const float4* Ar0 = (const float4*)As[i0];
    const float4* Ar1 = (const float4*)As[i0 + 1];
    const float4* Br  = (const float4*)Bs[jl];
    const float4* G4  = (const float4*)g1s;
    const float4* Bb4 = (const float4*)b1s;
    const float4* W4  = (const float4*)wchf;

    // pass 1: mean/var for both rows
    float s0 = 0.f, q0 = 0.f, s1 = 0.f, q1 = 0.f;
#pragma unroll 8
    for (int kq = 0; kq < 64; ++kq) {
        float4 a0 = Ar0[kq], a1 = Ar1[kq], bv = Br[kq];
        float h;
        h = a0.x + bv.x; s0 += h; q0 = fmaf(h, h, q0);
        h = a0.y + bv.y; s0 += h; q0 = fmaf(h, h, q0);
        h = a0.z + bv.z; s0 += h; q0 = fmaf(h, h, q0);
        h = a0.w + bv.w; s0 += h; q0 = fmaf(h, h, q0);
        h = a1.x + bv.x; s1 += h; q1 = fmaf(h, h, q1);
        h = a1.y + bv.y; s1 += h; q1 = fmaf(h, h, q1);
        h = a1.z + bv.z; s1 += h; q1 = fmaf(h, h, q1);
        h = a1.w + bv.w; s1 += h; q1 = fmaf(h, h, q1);
    }
    const float inv256 = 1.f / 256.f;
    float mn0 = s0 * inv256, mn1 = s1 * inv256;
    float r0 = rsqrtf(q0 * inv256 - mn0 * mn0 + 1e-5f);
    float r1 = rsqrtf(q1 * inv256 - mn1 * mn1 + 1e-5f);
    float c0 = -mn0 * r0, c1 = -mn1 * r1;

    float acc0[8], acc1[8];
#pragma unroll
    for (int c = 0; c < 8; ++c) { acc0[c] = 0.f; acc1[c] = 0.f; }

#define STEP(AE0, AE1, BE, GE, BBE, WIDX) do {                                   \
        float h0 = (AE0) + (BE);                                                 \
        float x0 = fmaf(h0, r0, c0); x0 = fmaf(x0, (GE), (BBE));                 \
        float y0 = 0.5f * x0 * (1.f + erff(x0 * 0.70710678118654752f));          \
        float h1 = (AE1) + (BE);                                                 \
        float x1 = fmaf(h1, r1, c1); x1 = fmaf(x1, (GE), (BBE));                 \
        float y1 = 0.5f * x1 * (1.f + erff(x1 * 0.70710678118654752f));          \
        float4 wa = W4[2 * (WIDX)], wb = W4[2 * (WIDX) + 1];                     \
        acc0[0] = fmaf(y0, wa.x, acc0[0]); acc1[0] = fmaf(y1, wa.x, acc1[0]);    \
        acc0[1] = fmaf(y0, wa.y, acc0[1]); acc1[1] = fmaf(y1, wa.y, acc1[1]);    \
        acc0[2] = fmaf(y0, wa.z, acc0[2]); acc1[2] = fmaf(y1, wa.z, acc1[2]);    \
        acc0[3] = fmaf(y0, wa.w, acc0[3]); acc1[3] = fmaf(y1, wa.w, acc1[3]);    \
        acc0[4] = fmaf(y0, wb.x, acc0[4]); acc1[4] = fmaf(y1, wb.x, acc1[4]);    \
        acc0[5] = fmaf(y0, wb.y, acc0[5]); acc1[5] = fmaf(y1, wb.y, acc1[5]);    \
        acc0[6] = fmaf(y0, wb.z, acc0[6]); acc1[6] = fmaf(y1, wb.z, acc1[6]);    \
        acc0[7] = fmaf(y0, wb.w, acc0[7]); acc1[7] = fmaf(y1, wb.w, acc1[7]);    \
    } while (0)

#pragma unroll 4
    for (int kq = 0; kq < 64; ++kq) {
        float4 a0 = Ar0[kq], a1 = Ar1[kq], bv = Br[kq];
        float4 g4 = G4[kq], bb4 = Bb4[kq];
        STEP(a0.x, a1.x, bv.x, g4.x, bb4.x, 4 * kq + 0);
        STEP(a0.y, a1.y, bv.y, g4.y, bb4.y, 4 * kq + 1);
        STEP(a0.z, a1.z, bv.z, g4.z, bb4.z, 4 * kq + 2);
        STEP(a0.w, a1.w, bv.w, g4.w, bb4.w, 4 * kq + 3);
    }
#undef STEP

    int i = it * 32 + i0;
    int j = jt * 16 + jl;
    float mk0 = masks[(size_t)(b * 256 + i) * 256 + j];
    float mk1 = masks[(size_t)(b * 256 + i + 1) * 256 + j];
    float* dst0 = out + ((size_t)(b * 256 + i) * 256 + j) * 8;
    float* dst1 = out + ((size_t)(b * 256 + i + 1) * 256 + j) * 8;
    float4 oA, oB;
    oA.x = (acc0[0] + bcs[0]) * mk0; oA.y = (acc0[1] + bcs[1]) * mk0;
    oA.z = (acc0[2] + bcs[2]) * mk0; oA.w = (acc0[3] + bcs[3]) * mk0;
    oB.x = (acc0[4] + bcs[4]) * mk0; oB.y = (acc0[5] + bcs[5]) * mk0;
    oB.z = (acc0[6] + bcs[6]) * mk0; oB.w = (acc0[7] + bcs[7]) * mk0;
    *(float4*)(dst0)     = oA;
    *(float4*)(dst0 + 4) = oB;
    oA.x = (acc1[0] + bcs[0]) * mk1; oA.y = (acc1[1] + bcs[1]) * mk1;
    oA.z = (acc1[2] + bcs[2]) * mk1; oA.w = (acc1[3] + bcs[3]) * mk1;
    oB.x = (acc1[4] + bcs[4]) * mk1; oB.y = (acc1[5] + bcs[5]) * mk1;
    oB.z = (acc1[6] + bcs[6]) * mk1; oB.w = (acc1[7] + bcs[7]) * mk1;
    *(float4*)(dst1)     = oA;
    *(float4*)(dst1 + 4) = oB;
}

// ---------------- launch ----------------
extern "C" void kernel_launch(void* const* d_in, const int* in_sizes, int n_in,
                              void* d_out, int out_size, void* d_ws, size_t ws_size,
                              hipStream_t stream) {
    (void)in_sizes; (void)n_in; (void)out_size; (void)ws_size;
    const float* emb_in = (const float*)d_in[0];
    const float* masks  = (const float*)d_in[1];
    const int* ast = (const int*)d_in[2];
    const int* aed = (const int*)d_in[3];
    const int* ost = (const int*)d_in[4];
    const int* oed = (const int*)d_in[5];
    const int* sid = (const int*)d_in[6];
    const float* E    = (const float*)d_in[7];
    const float* Wtp  = (const float*)d_in[8];
    const float* btp  = (const float*)d_in[9];
    const float* Wat  = (const float*)d_in[10];
    const float* bat  = (const float*)d_in[11];
    const float* Wg   = (const float*)d_in[12];
    const float* bg   = (const float*)d_in[13];
    const float* g0   = (const float*)d_in[14];
    const float* b0   = (const float*)d_in[15];
    const float* W1   = (const float*)d_in[16];
    const float* bl1  = (const float*)d_in[17];
    const float* g1   = (const float*)d_in[18];
    const float* b1   = (const float*)d_in[19];
    const float* Wc   = (const float*)d_in[20];
    const float* bc   = (const float*)d_in[21];
    const float* Wc1  = (const float*)d_in[22];
    const float* bc1  = (const float*)d_in[23];
    float* outp = (float*)d_out;

    float* fw = (float*)d_ws;
    float* emb = fw;                                  // 786432 f32
    float* nf  = emb + 786432;                        // 49152 f32
    float* wts = nf + 49152;                          // 1024 f32
    float* ae  = wts + 1024;                          // 128 f32
    int*   hasin = (int*)(ae + 128);                  // 64 i32
    float* hasedge = (float*)(hasin + 64);            // 4 f32
    float* abm = fw + 836864;                         // 524288 f32 (16B aligned)

    k_ln0<<<1024, 256, 0, stream>>>(emb_in, g0, b0, emb);
    k_nf<<<64, 256, 0, stream>>>(emb, ast, aed, ost, oed, sid, Wtp, btp, nf);
    k_graph<<<4, 256, 0, stream>>>(nf, ast, aed, ost, oed, E, Wat, bat, wts, ae, hasin, hasedge);
    k_upd<<<64, 256, 0, stream>>>(nf, wts, ae, hasin, hasedge, ast, ost, E, Wg, bg, emb);
    dim3 gg(16, 32);
    k_gemm32<<<gg, 256, 0, stream>>>(emb, W1, abm);
    dim3 g6(16, 8, 4);
    k_hidden<<<g6, 256, 0, stream>>>(abm, masks, bl1, g1, b1, Wc, bc, Wc1, bc1, outp);
}

// Round 5
// 399.055 us; speedup vs baseline: 1.6039x; 1.6039x over previous
//
#include <hip/hip_runtime.h>

// dims
#define Bn 4
#define Ln 256
#define Hn 768
#define Tn 16

// ---------------- K1: LayerNorm over H (fp32 in/out) ----------------
__global__ __launch_bounds__(256) void k_ln0(const float* __restrict__ x,
                                             const float* __restrict__ g,
                                             const float* __restrict__ be,
                                             float* __restrict__ out) {
    int row = blockIdx.x, tid = threadIdx.x;
    const float* xr = x + (size_t)row * Hn;
    float v0 = xr[tid], v1 = xr[tid + 256], v2 = xr[tid + 512];
    float s = v0 + v1 + v2;
    float q = v0 * v0 + v1 * v1 + v2 * v2;
    __shared__ float sm[4], qm[4];
    for (int o = 32; o > 0; o >>= 1) { s += __shfl_down(s, o); q += __shfl_down(q, o); }
    if ((tid & 63) == 0) { sm[tid >> 6] = s; qm[tid >> 6] = q; }
    __syncthreads();
    float S = sm[0] + sm[1] + sm[2] + sm[3];
    float Q = qm[0] + qm[1] + qm[2] + qm[3];
    float mean = S * (1.f / 768.f);
    float rstd = rsqrtf(Q * (1.f / 768.f) - mean * mean + 1e-5f);
    float* o0 = out + (size_t)row * Hn;
    o0[tid]       = (v0 - mean) * rstd * g[tid]       + be[tid];
    o0[tid + 256] = (v1 - mean) * rstd * g[tid + 256] + be[tid + 256];
    o0[tid + 512] = (v2 - mean) * rstd * g[tid + 512] + be[tid + 512];
}

// ---------------- K2: span means -> xv[64][1568] (padded with zeros) ----------
__global__ __launch_bounds__(256) void k_spans(const float* __restrict__ emb,
                                               const int* __restrict__ ast_, const int* __restrict__ aed_,
                                               const int* __restrict__ ost_, const int* __restrict__ oed_,
                                               const int* __restrict__ sid_,
                                               float* __restrict__ xv) {
    int n = blockIdx.x, b = n >> 4, tid = threadIdx.x;
    int ast = ast_[n], aed = aed_[n], ost = ost_[n], oed = oed_[n], sid = sid_[n];
    float ai = 1.f / (float)(aed - ast + 1);
    float oi = 1.f / (float)(oed - ost + 1);
    const float* eb = emb + (size_t)b * Ln * Hn;
    float* xr = xv + (size_t)n * 1568;
    for (int r = tid; r < 1568; r += 256) {
        float v;
        if (r < 768) {
            float s = 0.f;
            for (int l = ast; l <= aed; ++l) s += eb[l * Hn + r];
            v = s * ai;
        } else if (r < 1536) {
            int h = r - 768;
            float s = 0.f;
            for (int l = ost; l <= oed; ++l) s += eb[l * Hn + h];
            v = s * oi;
        } else if (r < 1539) {
            v = (sid - 2 == r - 1536) ? 1.f : 0.f;
        } else {
            v = 0.f;
        }
        xr[r] = v;
    }
}

// ---------------- skinny tiled GEMM: C[M x 768] = A[M x Kpad] @ B[Kb x 768] + bias
// rows of B with index >= Kb are treated as zero (A is zero-padded already)
__global__ __launch_bounds__(256) void k_skinny(const float* __restrict__ A,
                                                const float* __restrict__ B,
                                                const float* __restrict__ bias,
                                                float* __restrict__ C,
                                                int Kpad, int Kb) {
    __shared__ float At[32][33], Bt[32][33];
    int tid = threadIdx.x;
    int n0 = blockIdx.x * 32, m0 = blockIdx.y * 32;
    int lr = tid >> 3, lc = (tid & 7) * 4;
    int tm = tid >> 3, tn4 = (tid & 7) * 4;
    float acc0 = 0.f, acc1 = 0.f, acc2 = 0.f, acc3 = 0.f;
    for (int k0 = 0; k0 < Kpad; k0 += 32) {
        float4 av = *(const float4*)(A + (size_t)(m0 + lr) * Kpad + k0 + lc);
        At[lr][lc] = av.x; At[lr][lc + 1] = av.y; At[lr][lc + 2] = av.z; At[lr][lc + 3] = av.w;
        int gk = k0 + lr;
        float4 bv = {0.f, 0.f, 0.f, 0.f};
        if (gk < Kb) bv = *(const float4*)(B + (size_t)gk * 768 + n0 + lc);
        Bt[lr][lc] = bv.x; Bt[lr][lc + 1] = bv.y; Bt[lr][lc + 2] = bv.z; Bt[lr][lc + 3] = bv.w;
        __syncthreads();
#pragma unroll
        for (int k = 0; k < 32; ++k) {
            float a = At[tm][k];
            acc0 = fmaf(a, Bt[k][tn4], acc0);
            acc1 = fmaf(a, Bt[k][tn4 + 1], acc1);
            acc2 = fmaf(a, Bt[k][tn4 + 2], acc2);
            acc3 = fmaf(a, Bt[k][tn4 + 3], acc3);
        }
        __syncthreads();
    }
    float* dst = C + (size_t)(m0 + tm) * 768 + n0 + tn4;
    dst[0] = acc0 + bias[n0 + tn4];
    dst[1] = acc1 + bias[n0 + tn4 + 1];
    dst[2] = acc2 + bias[n0 + tn4 + 2];
    dst[3] = acc3 + bias[n0 + tn4 + 3];
}

// ---------------- K4: graph attention (LDS-staged) ----------------
__global__ __launch_bounds__(256) void k_graph(const float* __restrict__ nf,
                                               const int* __restrict__ ast_, const int* __restrict__ aed_,
                                               const int* __restrict__ ost_, const int* __restrict__ oed_,
                                               const float* __restrict__ E,
                                               const float* __restrict__ Wat,
                                               const float* __restrict__ bat,
                                               float* __restrict__ w_out, float* __restrict__ ae_out,
                                               int* __restrict__ hasin, float* __restrict__ hasedge) {
    int b = blockIdx.x, tid = threadIdx.x;
    __shared__ float nfs[16][780];
    __shared__ int ast[16], aed[16], ost[16], oed[16];
    __shared__ float red[256];
    __shared__ float nrm[16], p[16], q[16], rr[2];
    __shared__ unsigned m0b[16], m1b[16];
    const float* nfb = nf + (size_t)b * 16 * Hn;
    for (int e = tid; e < 3072; e += 256) {
        int r = e / 192, c = (e - r * 192) * 4;
        float4 v = *(const float4*)(nfb + r * Hn + c);
        nfs[r][c] = v.x; nfs[r][c + 1] = v.y; nfs[r][c + 2] = v.z; nfs[r][c + 3] = v.w;
    }
    if (tid < 16) {
        int n = b * 16 + tid;
        ast[tid] = ast_[n]; aed[tid] = aed_[n]; ost[tid] = ost_[n]; oed[tid] = oed_[n];
        m0b[tid] = 0u; m1b[tid] = 0u;
    }
    __syncthreads();
    int t = tid >> 4, lane = tid & 15;
    float ss = 0.f, pp = 0.f, qq = 0.f;
    for (int h = lane; h < 768; h += 16) {
        float v = nfs[t][h];
        ss = fmaf(v, v, ss);
        float lr = v > 0.f ? v : 0.2f * v;
        pp = fmaf(lr, Wat[h], pp);
        qq = fmaf(lr, Wat[768 + h], qq);
    }
    red[tid] = ss; __syncthreads();
    if (tid < 16) { float s = 0.f; for (int k2 = 0; k2 < 16; ++k2) s += red[tid * 16 + k2]; nrm[tid] = sqrtf(s); }
    __syncthreads();
    red[tid] = pp; __syncthreads();
    if (tid < 16) { float s = 0.f; for (int k2 = 0; k2 < 16; ++k2) s += red[tid * 16 + k2]; p[tid] = s; }
    __syncthreads();
    red[tid] = qq; __syncthreads();
    if (tid < 16) { float s = 0.f; for (int k2 = 0; k2 < 16; ++k2) s += red[tid * 16 + k2]; q[tid] = s; }
    __syncthreads();
    float rp = 0.f;
    if (tid < 32) {
        int e = tid >> 4;
        for (int h = lane; h < 768; h += 16) {
            float v = E[e * 768 + h];
            float lr = v > 0.f ? v : 0.2f * v;
            rp = fmaf(lr, Wat[1536 + h], rp);
        }
    }
    red[tid] = rp; __syncthreads();
    if (tid < 2) { float s = 0.f; for (int k2 = 0; k2 < 16; ++k2) s += red[tid * 16 + k2]; rr[tid] = s; }
    __syncthreads();
    // cosine sim from LDS, edge masks
    {
        int i = tid >> 4, j = tid & 15;
        float dot = 0.f;
#pragma unroll 8
        for (int h = 0; h < 768; ++h) dot = fmaf(nfs[i][h], nfs[j][h], dot);
        float sim = dot / (fmaxf(nrm[i], 1e-8f) * fmaxf(nrm[j], 1e-8f));
        bool ok = (sim > 0.f) && (i != j);
        if (ok && ast[i] == ast[j] && aed[i] == aed[j]) atomicOr(&m0b[i], 1u << j);
        if (ok && ost[i] == ost[j] && oed[i] == oed[j]) atomicOr(&m1b[i], 1u << j);
    }
    __syncthreads();
    if (tid < 16) {
        int tt = tid;
        float battn = bat[0];
        float sc[32];
        float mx = -3.4e38f;
        bool hi = false;
#pragma unroll
        for (int s = 0; s < 16; ++s) {
            bool e0 = (m0b[s] >> tt) & 1u;   // emask[t,s,0] = m0[s,t]
            bool e1 = (m1b[s] >> tt) & 1u;
            float base = p[tt] + q[s] + battn;
            float v0 = e0 ? (base + rr[0]) : -1e9f;
            float v1 = e1 ? (base + rr[1]) : -1e9f;
            sc[2 * s] = v0; sc[2 * s + 1] = v1;
            mx = fmaxf(mx, fmaxf(v0, v1));
            hi = hi || e0 || e1;
        }
        float sum = 0.f;
#pragma unroll
        for (int k2 = 0; k2 < 32; ++k2) { float e = expf(sc[k2] - mx); sc[k2] = e; sum += e; }
        float inv = 1.f / sum;
        float ae0 = 0.f, ae1 = 0.f;
#pragma unroll
        for (int s = 0; s < 16; ++s) {
            float w0 = sc[2 * s] * inv, w1 = sc[2 * s + 1] * inv;
            w_out[(size_t)(b * 16 + tt) * 16 + s] = w0 + w1;
            ae0 += w0; ae1 += w1;
        }
        ae_out[(b * 16 + tt) * 2 + 0] = ae0;
        ae_out[(b * 16 + tt) * 2 + 1] = ae1;
        hasin[b * 16 + tt] = hi ? 1 : 0;
        red[tid] = hi ? 1.f : 0.f;
    }
    __syncthreads();
    if (tid == 0) {
        float he = 0.f;
        for (int k2 = 0; k2 < 16; ++k2) he = fmaxf(he, red[k2]);
        hasedge[b] = he;
    }
}

// ---------------- K5a: aggregate messages -> agg[64][1536] ----------------
__global__ __launch_bounds__(256) void k_agg(const float* __restrict__ nf,
                                             const float* __restrict__ w, const float* __restrict__ ae,
                                             const float* __restrict__ E,
                                             float* __restrict__ agg) {
    int n = blockIdx.x, b = n >> 4, tid = threadIdx.x;
    __shared__ float nfs[16][768];
    __shared__ float ws[16];
    const float* nfb = nf + (size_t)b * 16 * Hn;
    for (int e = tid; e < 3072; e += 256) {
        int r = e / 192, c = (e - r * 192) * 4;
        *(float4*)&nfs[r][c] = *(const float4*)(nfb + r * Hn + c);
    }
    if (tid < 16) ws[tid] = w[(size_t)n * 16 + tid];
    __syncthreads();
    float ae0 = ae[2 * n], ae1 = ae[2 * n + 1];
    float* ag = agg + (size_t)n * 1536;
    for (int f = tid; f < 768; f += 256) {
        float s = 0.f;
#pragma unroll
        for (int s16 = 0; s16 < 16; ++s16) s = fmaf(ws[s16], nfs[s16][f], s);
        ag[f] = s;
        ag[768 + f] = ae0 * E[f] + ae1 * E[768 + f];
    }
}

// ---------------- K5b: select + scatter-add into emb ----------------
__global__ __launch_bounds__(256) void k_scatter(const float* __restrict__ raw,
                                                 const float* __restrict__ nf,
                                                 const int* __restrict__ hasin, const float* __restrict__ hasedge,
                                                 const int* __restrict__ ast_, const int* __restrict__ ost_,
                                                 float* __restrict__ emb) {
    int n = blockIdx.x, b = n >> 4, tid = threadIdx.x;
    if (hasedge[b] == 0.f) return;
    int center = (ast_[n] + ost_[n]) >> 1;
    float* dst = emb + (size_t)(b * Ln + center) * Hn;
    int hi = hasin[n];
    const float* src = hi ? (raw + (size_t)n * Hn) : (nf + (size_t)n * Hn);
    for (int h = tid; h < 768; h += 256) {
        float v = src[h];
        if (hi) v = fmaxf(v, 0.f);
        atomicAdd(&dst[h], v);
    }
}

// ---------------- K7: fp32 tiled GEMM  abm[1024][512] ----------------
__global__ __launch_bounds__(256) void k_gemm32(const float* __restrict__ emb,
                                                const float* __restrict__ W1,
                                                float* __restrict__ abm) {
    __shared__ float At[32][33], Bt[32][33];
    int tid = threadIdx.x;
    int m0 = blockIdx.y * 32, n0 = blockIdx.x * 32;
    int tm = tid >> 3, tn4 = (tid & 7) * 4;
    float acc0 = 0.f, acc1 = 0.f, acc2 = 0.f, acc3 = 0.f;
    int lr = tid >> 3, lc = (tid & 7) * 4;
    for (int k0 = 0; k0 < 768; k0 += 32) {
        float4 av = *(const float4*)(emb + (size_t)(m0 + lr) * 768 + k0 + lc);
        At[lr][lc] = av.x; At[lr][lc + 1] = av.y; At[lr][lc + 2] = av.z; At[lr][lc + 3] = av.w;
        int gk = k0 + lr;
        int gn = n0 + lc;
        const float* src = (gn < 256) ? (W1 + (size_t)gk * 256 + gn)
                                      : (W1 + (size_t)(768 + gk) * 256 + (gn - 256));
        float4 bv = *(const float4*)src;
        Bt[lr][lc] = bv.x; Bt[lr][lc + 1] = bv.y; Bt[lr][lc + 2] = bv.z; Bt[lr][lc + 3] = bv.w;
        __syncthreads();
#pragma unroll
        for (int k = 0; k < 32; ++k) {
            float a = At[tm][k];
            acc0 = fmaf(a, Bt[k][tn4], acc0);
            acc1 = fmaf(a, Bt[k][tn4 + 1], acc1);
            acc2 = fmaf(a, Bt[k][tn4 + 2], acc2);
            acc3 = fmaf(a, Bt[k][tn4 + 3], acc3);
        }
        __syncthreads();
    }
    float* dst = abm + (size_t)(m0 + tm) * 512 + n0 + tn4;
    dst[0] = acc0; dst[1] = acc1; dst[2] = acc2; dst[3] = acc3;
}

// ---------------- K8: fused LN+GELU+proj over [B,L,L,L] — fp32 output ----------
__global__ __launch_bounds__(256) void k_hidden(const float* __restrict__ abm,
                                                const float* __restrict__ masks,
                                                const float* __restrict__ bl1,
                                                const float* __restrict__ g1,
                                                const float* __restrict__ b1,
                                                const float* __restrict__ Wc,
                                                const float* __restrict__ bc,
                                                const float* __restrict__ Wc1,
                                                const float* __restrict__ bc1,
                                                float* __restrict__ out) {
    __shared__ __align__(16) float As[32][260];
    __shared__ __align__(16) float Bs[16][260];
    __shared__ __align__(16) float g1s[256];
    __shared__ __align__(16) float b1s[256];
    __shared__ __align__(16) float wchf[256][8];
    __shared__ float bcs[8];
    int tid = threadIdx.x;
    int jt = blockIdx.x, it = blockIdx.y, b = blockIdx.z;
    const float* Ag = abm + (size_t)(b * 256 + it * 32) * 512;
    const float* Bg = abm + (size_t)(b * 256 + jt * 16) * 512 + 256;
#pragma unroll
    for (int u = 0; u < 32; ++u) {
        As[u][tid] = Ag[u * 512 + tid];
    }
#pragma unroll
    for (int u = 0; u < 16; ++u) {
        Bs[u][tid] = Bg[u * 512 + tid] + bl1[tid];
    }
    g1s[tid] = g1[tid];
    b1s[tid] = b1[tid];
    {
        int k = tid;
#pragma unroll
        for (int c = 0; c < 6; ++c) wchf[k][c] = Wc[k * 6 + c];
        wchf[k][6] = Wc1[k * 2];
        wchf[k][7] = Wc1[k * 2 + 1];
    }
    if (tid < 6) bcs[tid] = bc[tid];
    else if (tid < 8) bcs[tid] = bc1[tid - 6];
    __syncthreads();

    int i0 = (tid >> 4) * 2;
    int jl = tid & 15;
    const float4* Ar0 = (const float4*)As[i0];
    const float4* Ar1 = (const float4*)As[i0 + 1];
    const float4* Br  = (const float4*)Bs[jl];
    const float4* G4  = (const float4*)g1s;
    const float4* Bb4 = (const float4*)b1s;
    const float4* W4  = (const float4*)wchf;

    // pass 1: mean/var for both rows
    float s0 = 0.f, q0 = 0.f, s1 = 0.f, q1 = 0.f;
#pragma unroll 8
    for (int kq = 0; kq < 64; ++kq) {
        float4 a0 = Ar0[kq], a1 = Ar1[kq], bv = Br[kq];
        float h;
        h = a0.x + bv.x; s0 += h; q0 = fmaf(h, h, q0);
        h = a0.y + bv.y; s0 += h; q0 = fmaf(h, h, q0);
        h = a0.z + bv.z; s0 += h; q0 = fmaf(h, h, q0);
        h = a0.w + bv.w; s0 += h; q0 = fmaf(h, h, q0);
        h = a1.x + bv.x; s1 += h; q1 = fmaf(h, h, q1);
        h = a1.y + bv.y; s1 += h; q1 = fmaf(h, h, q1);
        h = a1.z + bv.z; s1 += h; q1 = fmaf(h, h, q1);
        h = a1.w + bv.w; s1 += h; q1 = fmaf(h, h, q1);
    }
    const float inv256 = 1.f / 256.f;
    float mn0 = s0 * inv256, mn1 = s1 * inv256;
    float r0 = rsqrtf(q0 * inv256 - mn0 * mn0 + 1e-5f);
    float r1 = rsqrtf(q1 * inv256 - mn1 * mn1 + 1e-5f);
    float c0 = -mn0 * r0, c1 = -mn1 * r1;

    float acc0[8], acc1[8];
#pragma unroll
    for (int c = 0; c < 8; ++c) { acc0[c] = 0.f; acc1[c] = 0.f; }

#define STEP(AE0, AE1, BE, GE, BBE, WIDX) do {                                   \
        float h0 = (AE0) + (BE);                                                 \
        float x0 = fmaf(h0, r0, c0); x0 = fmaf(x0, (GE), (BBE));                 \
        float y0 = 0.5f * x0 * (1.f + erff(x0 * 0.70710678118654752f));          \
        float h1 = (AE1) + (BE);                                                 \
        float x1 = fmaf(h1, r1, c1); x1 = fmaf(x1, (GE), (BBE));                 \
        float y1 = 0.5f * x1 * (1.f + erff(x1 * 0.70710678118654752f));          \
        float4 wa = W4[2 * (WIDX)], wb = W4[2 * (WIDX) + 1];                     \
        acc0[0] = fmaf(y0, wa.x, acc0[0]); acc1[0] = fmaf(y1, wa.x, acc1[0]);    \
        acc0[1] = fmaf(y0, wa.y, acc0[1]); acc1[1] = fmaf(y1, wa.y, acc1[1]);    \
        acc0[2] = fmaf(y0, wa.z, acc0[2]); acc1[2] = fmaf(y1, wa.z, acc1[2]);    \
        acc0[3] = fmaf(y0, wa.w, acc0[3]); acc1[3] = fmaf(y1, wa.w, acc1[3]);    \
        acc0[4] = fmaf(y0, wb.x, acc0[4]); acc1[4] = fmaf(y1, wb.x, acc1[4]);    \
        acc0[5] = fmaf(y0, wb.y, acc0[5]); acc1[5] = fmaf(y1, wb.y, acc1[5]);    \
        acc0[6] = fmaf(y0, wb.z, acc0[6]); acc1[6] = fmaf(y1, wb.z, acc1[6]);    \
        acc0[7] = fmaf(y0, wb.w, acc0[7]); acc1[7] = fmaf(y1, wb.w, acc1[7]);    \
    } while (0)

#pragma unroll 4
    for (int kq = 0; kq < 64; ++kq) {
        float4 a0 = Ar0[kq], a1 = Ar1[kq], bv = Br[kq];
        float4 g4 = G4[kq], bb4 = Bb4[kq];
        STEP(a0.x, a1.x, bv.x, g4.x, bb4.x, 4 * kq + 0);
        STEP(a0.y, a1.y, bv.y, g4.y, bb4.y, 4 * kq + 1);
        STEP(a0.z, a1.z, bv.z, g4.z, bb4.z, 4 * kq + 2);
        STEP(a0.w, a1.w, bv.w, g4.w, bb4.w, 4 * kq + 3);
    }
#undef STEP

    int i = it * 32 + i0;
    int j = jt * 16 + jl;
    float mk0 = masks[(size_t)(b * 256 + i) * 256 + j];
    float mk1 = masks[(size_t)(b * 256 + i + 1) * 256 + j];
    float* dst0 = out + ((size_t)(b * 256 + i) * 256 + j) * 8;
    float* dst1 = out + ((size_t)(b * 256 + i + 1) * 256 + j) * 8;
    float4 oA, oB;
    oA.x = (acc0[0] + bcs[0]) * mk0; oA.y = (acc0[1] + bcs[1]) * mk0;
    oA.z = (acc0[2] + bcs[2]) * mk0; oA.w = (acc0[3] + bcs[3]) * mk0;
    oB.x = (acc0[4] + bcs[4]) * mk0; oB.y = (acc0[5] + bcs[5]) * mk0;
    oB.z = (acc0[6] + bcs[6]) * mk0; oB.w = (acc0[7] + bcs[7]) * mk0;
    *(float4*)(dst0)     = oA;
    *(float4*)(dst0 + 4) = oB;
    oA.x = (acc1[0] + bcs[0]) * mk1; oA.y = (acc1[1] + bcs[1]) * mk1;
    oA.z = (acc1[2] + bcs[2]) * mk1; oA.w = (acc1[3] + bcs[3]) * mk1;
    oB.x = (acc1[4] + bcs[4]) * mk1; oB.y = (acc1[5] + bcs[5]) * mk1;
    oB.z = (acc1[6] + bcs[6]) * mk1; oB.w = (acc1[7] + bcs[7]) * mk1;
    *(float4*)(dst1)     = oA;
    *(float4*)(dst1 + 4) = oB;
}

// ---------------- launch ----------------
extern "C" void kernel_launch(void* const* d_in, const int* in_sizes, int n_in,
                              void* d_out, int out_size, void* d_ws, size_t ws_size,
                              hipStream_t stream) {
    (void)in_sizes; (void)n_in; (void)out_size; (void)ws_size;
    const float* emb_in = (const float*)d_in[0];
    const float* masks  = (const float*)d_in[1];
    const int* ast = (const int*)d_in[2];
    const int* aed = (const int*)d_in[3];
    const int* ost = (const int*)d_in[4];
    const int* oed = (const int*)d_in[5];
    const int* sid = (const int*)d_in[6];
    const float* E    = (const float*)d_in[7];
    const float* Wtp  = (const float*)d_in[8];
    const float* btp  = (const float*)d_in[9];
    const float* Wat  = (const float*)d_in[10];
    const float* bat  = (const float*)d_in[11];
    const float* Wg   = (const float*)d_in[12];
    const float* bg   = (const float*)d_in[13];
    const float* g0   = (const float*)d_in[14];
    const float* b0   = (const float*)d_in[15];
    const float* W1   = (const float*)d_in[16];
    const float* bl1  = (const float*)d_in[17];
    const float* g1   = (const float*)d_in[18];
    const float* b1   = (const float*)d_in[19];
    const float* Wc   = (const float*)d_in[20];
    const float* bc   = (const float*)d_in[21];
    const float* Wc1  = (const float*)d_in[22];
    const float* bc1  = (const float*)d_in[23];
    float* outp = (float*)d_out;

    float* fw = (float*)d_ws;
    float* emb = fw;                                  // 786432
    float* nf  = emb + 786432;                        // 49152
    float* wts = nf + 49152;                          // 1024   @835584
    float* ae  = wts + 1024;                          // 128    @836608
    int*   hasin = (int*)(ae + 128);                  // 64     @836736
    float* hasedge = (float*)(hasin + 64);            // 4      @836800
    float* xv  = fw + 836864;                         // 100352 (64x1568)
    float* agg = fw + 937216;                         // 98304  (64x1536)
    float* raw = fw + 1035520;                        // 49152  (64x768)
    float* abm = fw + 1084672;                        // 524288

    k_ln0<<<1024, 256, 0, stream>>>(emb_in, g0, b0, emb);
    k_spans<<<64, 256, 0, stream>>>(emb, ast, aed, ost, oed, sid, xv);
    dim3 gs(24, 2);
    k_skinny<<<gs, 256, 0, stream>>>(xv, Wtp, btp, nf, 1568, 1539);
    k_graph<<<4, 256, 0, stream>>>(nf, ast, aed, ost, oed, E, Wat, bat, wts, ae, hasin, hasedge);
    k_agg<<<64, 256, 0, stream>>>(nf, wts, ae, E, agg);
    k_skinny<<<gs, 256, 0, stream>>>(agg, Wg, bg, raw, 1536, 1536);
    k_scatter<<<64, 256, 0, stream>>>(raw, nf, hasin, hasedge, ast, ost, emb);
    dim3 gg(16, 32);
    k_gemm32<<<gg, 256, 0, stream>>>(emb, W1, abm);
    dim3 g6(16, 8, 4);
    k_hidden<<<g6, 256, 0, stream>>>(abm, masks, bl1, g1, b1, Wc, bc, Wc1, bc1, outp);
}

// Round 6
// 253.855 us; speedup vs baseline: 2.5214x; 1.5720x over previous
//
#include <hip/hip_runtime.h>

// ---------------- helpers ----------------
__device__ __forceinline__ unsigned short f2bf(float f) {
    union { float f; unsigned u; } v; v.f = f;
    unsigned u = v.u;
    unsigned r = (u + 0x7fffu + ((u >> 16) & 1u)) >> 16;
    return (unsigned short)r;
}
__device__ __forceinline__ float blo(unsigned u) {
    union { unsigned v; float f; } x; x.v = u << 16; return x.f;
}
__device__ __forceinline__ float bhi(unsigned u) {
    union { unsigned v; float f; } x; x.v = u & 0xffff0000u; return x.f;
}

typedef __attribute__((ext_vector_type(8))) short short8;
typedef __attribute__((ext_vector_type(4))) float floatx4;

// dims
#define Bn 4
#define Ln 256
#define Hn 768
#define Tn 16

// ---------------- K1: LayerNorm over H (fp32 in/out) ----------------
__global__ __launch_bounds__(256) void k_ln0(const float* __restrict__ x,
                                             const float* __restrict__ g,
                                             const float* __restrict__ be,
                                             float* __restrict__ out) {
    int row = blockIdx.x, tid = threadIdx.x;
    const float* xr = x + (size_t)row * Hn;
    float v0 = xr[tid], v1 = xr[tid + 256], v2 = xr[tid + 512];
    float s = v0 + v1 + v2;
    float q = v0 * v0 + v1 * v1 + v2 * v2;
    __shared__ float sm[4], qm[4];
    for (int o = 32; o > 0; o >>= 1) { s += __shfl_down(s, o); q += __shfl_down(q, o); }
    if ((tid & 63) == 0) { sm[tid >> 6] = s; qm[tid >> 6] = q; }
    __syncthreads();
    float S = sm[0] + sm[1] + sm[2] + sm[3];
    float Q = qm[0] + qm[1] + qm[2] + qm[3];
    float mean = S * (1.f / 768.f);
    float rstd = rsqrtf(Q * (1.f / 768.f) - mean * mean + 1e-5f);
    float* o0 = out + (size_t)row * Hn;
    o0[tid]       = (v0 - mean) * rstd * g[tid]       + be[tid];
    o0[tid + 256] = (v1 - mean) * rstd * g[tid + 256] + be[tid + 256];
    o0[tid + 512] = (v2 - mean) * rstd * g[tid + 512] + be[tid + 512];
}

// ---------------- K2: span means -> xv[64][1568]; also zero nf row ----------
__global__ __launch_bounds__(256) void k_spans(const float* __restrict__ emb,
                                               const int* __restrict__ ast_, const int* __restrict__ aed_,
                                               const int* __restrict__ ost_, const int* __restrict__ oed_,
                                               const int* __restrict__ sid_,
                                               float* __restrict__ xv,
                                               float* __restrict__ nf) {
    int n = blockIdx.x, b = n >> 4, tid = threadIdx.x;
    int ast = ast_[n], aed = aed_[n], ost = ost_[n], oed = oed_[n], sid = sid_[n];
    float ai = 1.f / (float)(aed - ast + 1);
    float oi = 1.f / (float)(oed - ost + 1);
    const float* eb = emb + (size_t)b * Ln * Hn;
    float* xr = xv + (size_t)n * 1568;
    for (int r = tid; r < 1568; r += 256) {
        float v;
        if (r < 768) {
            float s = 0.f;
            for (int l = ast; l <= aed; ++l) s += eb[l * Hn + r];
            v = s * ai;
        } else if (r < 1536) {
            int h = r - 768;
            float s = 0.f;
            for (int l = ost; l <= oed; ++l) s += eb[l * Hn + h];
            v = s * oi;
        } else if (r < 1539) {
            v = (sid - 2 == r - 1536) ? 1.f : 0.f;
        } else {
            v = 0.f;
        }
        xr[r] = v;
    }
    float* nr = nf + (size_t)n * Hn;
    nr[tid] = 0.f; nr[tid + 256] = 0.f; nr[tid + 512] = 0.f;
}

// ---------------- split-K skinny GEMM: C[M x 768] += A[M x Kpad] @ B[Kb x 768]
// chunk z covers k in [z*Kc, min(z*Kc+Kc, Kpad)); bias added by chunk 0.
__global__ __launch_bounds__(256) void k_skinny(const float* __restrict__ A,
                                                const float* __restrict__ B,
                                                const float* __restrict__ bias,
                                                float* __restrict__ C,
                                                int Kpad, int Kb, int Kc) {
    __shared__ float At[32][33], Bt[32][33];
    int tid = threadIdx.x;
    int n0 = blockIdx.x * 32, m0 = blockIdx.y * 32, z = blockIdx.z;
    int kbeg = z * Kc;
    int kend = kbeg + Kc; if (kend > Kpad) kend = Kpad;
    int lr = tid >> 3, lc = (tid & 7) * 4;
    int tm = tid >> 3, tn4 = (tid & 7) * 4;
    float acc0 = 0.f, acc1 = 0.f, acc2 = 0.f, acc3 = 0.f;
    for (int k0 = kbeg; k0 < kend; k0 += 32) {
        float4 av = *(const float4*)(A + (size_t)(m0 + lr) * Kpad + k0 + lc);
        At[lr][lc] = av.x; At[lr][lc + 1] = av.y; At[lr][lc + 2] = av.z; At[lr][lc + 3] = av.w;
        int gk = k0 + lr;
        float4 bv = {0.f, 0.f, 0.f, 0.f};
        if (gk < Kb) bv = *(const float4*)(B + (size_t)gk * 768 + n0 + lc);
        Bt[lr][lc] = bv.x; Bt[lr][lc + 1] = bv.y; Bt[lr][lc + 2] = bv.z; Bt[lr][lc + 3] = bv.w;
        __syncthreads();
#pragma unroll
        for (int k = 0; k < 32; ++k) {
            float a = At[tm][k];
            acc0 = fmaf(a, Bt[k][tn4], acc0);
            acc1 = fmaf(a, Bt[k][tn4 + 1], acc1);
            acc2 = fmaf(a, Bt[k][tn4 + 2], acc2);
            acc3 = fmaf(a, Bt[k][tn4 + 3], acc3);
        }
        __syncthreads();
    }
    if (z == 0) {
        acc0 += bias[n0 + tn4];
        acc1 += bias[n0 + tn4 + 1];
        acc2 += bias[n0 + tn4 + 2];
        acc3 += bias[n0 + tn4 + 3];
    }
    float* dst = C + (size_t)(m0 + tm) * 768 + n0 + tn4;
    atomicAdd(&dst[0], acc0);
    atomicAdd(&dst[1], acc1);
    atomicAdd(&dst[2], acc2);
    atomicAdd(&dst[3], acc3);
}

// ---------------- K4: graph attention (LDS-staged) ----------------
__global__ __launch_bounds__(256) void k_graph(const float* __restrict__ nf,
                                               const int* __restrict__ ast_, const int* __restrict__ aed_,
                                               const int* __restrict__ ost_, const int* __restrict__ oed_,
                                               const float* __restrict__ E,
                                               const float* __restrict__ Wat,
                                               const float* __restrict__ bat,
                                               float* __restrict__ w_out, float* __restrict__ ae_out,
                                               int* __restrict__ hasin, float* __restrict__ hasedge) {
    int b = blockIdx.x, tid = threadIdx.x;
    __shared__ float nfs[16][780];
    __shared__ int ast[16], aed[16], ost[16], oed[16];
    __shared__ float red[256];
    __shared__ float nrm[16], p[16], q[16], rr[2];
    __shared__ unsigned m0b[16], m1b[16];
    const float* nfb = nf + (size_t)b * 16 * Hn;
    for (int e = tid; e < 3072; e += 256) {
        int r = e / 192, c = (e - r * 192) * 4;
        float4 v = *(const float4*)(nfb + r * Hn + c);
        nfs[r][c] = v.x; nfs[r][c + 1] = v.y; nfs[r][c + 2] = v.z; nfs[r][c + 3] = v.w;
    }
    if (tid < 16) {
        int n = b * 16 + tid;
        ast[tid] = ast_[n]; aed[tid] = aed_[n]; ost[tid] = ost_[n]; oed[tid] = oed_[n];
        m0b[tid] = 0u; m1b[tid] = 0u;
    }
    __syncthreads();
    int t = tid >> 4, lane = tid & 15;
    float ss = 0.f, pp = 0.f, qq = 0.f;
    for (int h = lane; h < 768; h += 16) {
        float v = nfs[t][h];
        ss = fmaf(v, v, ss);
        float lr = v > 0.f ? v : 0.2f * v;
        pp = fmaf(lr, Wat[h], pp);
        qq = fmaf(lr, Wat[768 + h], qq);
    }
    red[tid] = ss; __syncthreads();
    if (tid < 16) { float s = 0.f; for (int k2 = 0; k2 < 16; ++k2) s += red[tid * 16 + k2]; nrm[tid] = sqrtf(s); }
    __syncthreads();
    red[tid] = pp; __syncthreads();
    if (tid < 16) { float s = 0.f; for (int k2 = 0; k2 < 16; ++k2) s += red[tid * 16 + k2]; p[tid] = s; }
    __syncthreads();
    red[tid] = qq; __syncthreads();
    if (tid < 16) { float s = 0.f; for (int k2 = 0; k2 < 16; ++k2) s += red[tid * 16 + k2]; q[tid] = s; }
    __syncthreads();
    float rp = 0.f;
    if (tid < 32) {
        int e = tid >> 4;
        for (int h = lane; h < 768; h += 16) {
            float v = E[e * 768 + h];
            float lr = v > 0.f ? v : 0.2f * v;
            rp = fmaf(lr, Wat[1536 + h], rp);
        }
    }
    red[tid] = rp; __syncthreads();
    if (tid < 2) { float s = 0.f; for (int k2 = 0; k2 < 16; ++k2) s += red[tid * 16 + k2]; rr[tid] = s; }
    __syncthreads();
    {
        int i = tid >> 4, j = tid & 15;
        float dot = 0.f;
#pragma unroll 8
        for (int h = 0; h < 768; ++h) dot = fmaf(nfs[i][h], nfs[j][h], dot);
        float sim = dot / (fmaxf(nrm[i], 1e-8f) * fmaxf(nrm[j], 1e-8f));
        bool ok = (sim > 0.f) && (i != j);
        if (ok && ast[i] == ast[j] && aed[i] == aed[j]) atomicOr(&m0b[i], 1u << j);
        if (ok && ost[i] == ost[j] && oed[i] == oed[j]) atomicOr(&m1b[i], 1u << j);
    }
    __syncthreads();
    if (tid < 16) {
        int tt = tid;
        float battn = bat[0];
        float sc[32];
        float mx = -3.4e38f;
        bool hi = false;
#pragma unroll
        for (int s = 0; s < 16; ++s) {
            bool e0 = (m0b[s] >> tt) & 1u;   // emask[t,s,0] = m0[s,t]
            bool e1 = (m1b[s] >> tt) & 1u;
            float base = p[tt] + q[s] + battn;
            float v0 = e0 ? (base + rr[0]) : -1e9f;
            float v1 = e1 ? (base + rr[1]) : -1e9f;
            sc[2 * s] = v0; sc[2 * s + 1] = v1;
            mx = fmaxf(mx, fmaxf(v0, v1));
            hi = hi || e0 || e1;
        }
        float sum = 0.f;
#pragma unroll
        for (int k2 = 0; k2 < 32; ++k2) { float e = expf(sc[k2] - mx); sc[k2] = e; sum += e; }
        float inv = 1.f / sum;
        float ae0 = 0.f, ae1 = 0.f;
#pragma unroll
        for (int s = 0; s < 16; ++s) {
            float w0 = sc[2 * s] * inv, w1 = sc[2 * s + 1] * inv;
            w_out[(size_t)(b * 16 + tt) * 16 + s] = w0 + w1;
            ae0 += w0; ae1 += w1;
        }
        ae_out[(b * 16 + tt) * 2 + 0] = ae0;
        ae_out[(b * 16 + tt) * 2 + 1] = ae1;
        hasin[b * 16 + tt] = hi ? 1 : 0;
        red[tid] = hi ? 1.f : 0.f;
    }
    __syncthreads();
    if (tid == 0) {
        float he = 0.f;
        for (int k2 = 0; k2 < 16; ++k2) he = fmaxf(he, red[k2]);
        hasedge[b] = he;
    }
}

// ---------------- K5a: aggregate messages -> agg[64][1536]; zero raw row ------
__global__ __launch_bounds__(256) void k_agg(const float* __restrict__ nf,
                                             const float* __restrict__ w, const float* __restrict__ ae,
                                             const float* __restrict__ E,
                                             float* __restrict__ agg,
                                             float* __restrict__ raw) {
    int n = blockIdx.x, b = n >> 4, tid = threadIdx.x;
    __shared__ float nfs[16][768];
    __shared__ float ws[16];
    const float* nfb = nf + (size_t)b * 16 * Hn;
    for (int e = tid; e < 3072; e += 256) {
        int r = e / 192, c = (e - r * 192) * 4;
        *(float4*)&nfs[r][c] = *(const float4*)(nfb + r * Hn + c);
    }
    if (tid < 16) ws[tid] = w[(size_t)n * 16 + tid];
    __syncthreads();
    float ae0 = ae[2 * n], ae1 = ae[2 * n + 1];
    float* ag = agg + (size_t)n * 1536;
    for (int f = tid; f < 768; f += 256) {
        float s = 0.f;
#pragma unroll
        for (int s16 = 0; s16 < 16; ++s16) s = fmaf(ws[s16], nfs[s16][f], s);
        ag[f] = s;
        ag[768 + f] = ae0 * E[f] + ae1 * E[768 + f];
    }
    float* rr = raw + (size_t)n * Hn;
    rr[tid] = 0.f; rr[tid + 256] = 0.f; rr[tid + 512] = 0.f;
}

// ---------------- K5b: select + scatter-add into emb ----------------
__global__ __launch_bounds__(256) void k_scatter(const float* __restrict__ raw,
                                                 const float* __restrict__ nf,
                                                 const int* __restrict__ hasin, const float* __restrict__ hasedge,
                                                 const int* __restrict__ ast_, const int* __restrict__ ost_,
                                                 float* __restrict__ emb) {
    int n = blockIdx.x, b = n >> 4, tid = threadIdx.x;
    if (hasedge[b] == 0.f) return;
    int center = (ast_[n] + ost_[n]) >> 1;
    float* dst = emb + (size_t)(b * Ln + center) * Hn;
    int hi = hasin[n];
    const float* src = hi ? (raw + (size_t)n * Hn) : (nf + (size_t)n * Hn);
    for (int h = tid; h < 768; h += 256) {
        float v = src[h];
        if (hi) v = fmaxf(v, 0.f);
        atomicAdd(&dst[h], v);
    }
}

// ---------------- K6a: emb fp32 -> bf16 ----------------
__global__ __launch_bounds__(256) void k_cvt(const float* __restrict__ in,
                                             unsigned short* __restrict__ out) {
    int i = (blockIdx.x * 256 + threadIdx.x) * 4;
    float4 v = *(const float4*)(in + i);
    ushort4 o;
    o.x = f2bf(v.x); o.y = f2bf(v.y); o.z = f2bf(v.z); o.w = f2bf(v.w);
    *(ushort4*)(out + i) = o;
}

// ---------------- K6b: W1[1536][256] fp32 -> w1t[512][768] bf16 (B^T) ----------
__global__ __launch_bounds__(256) void k_w1t(const float* __restrict__ W1,
                                             unsigned short* __restrict__ w1t) {
    __shared__ float tile[32][33];
    int kt = blockIdx.x, nt = blockIdx.y, tid = threadIdx.x;
    int k0 = kt * 32, n0 = nt * 32;
    int rowoff = (n0 < 256) ? 0 : 768;
    int col0 = n0 & 255;
    int r = tid >> 3, c = (tid & 7) * 4;
    float4 v = *(const float4*)(W1 + (size_t)(rowoff + k0 + r) * 256 + col0 + c);
    tile[r][c] = v.x; tile[r][c + 1] = v.y; tile[r][c + 2] = v.z; tile[r][c + 3] = v.w;
    __syncthreads();
    // write w1t[n0+r][k0+c..c+3] = tile[c..c+3][r]
    ushort4 o;
    o.x = f2bf(tile[c][r]); o.y = f2bf(tile[c + 1][r]);
    o.z = f2bf(tile[c + 2][r]); o.w = f2bf(tile[c + 3][r]);
    *(ushort4*)(w1t + (size_t)(n0 + r) * 768 + k0 + c) = o;
}

// ---------------- K7: MFMA GEMM  abm[1024][512] = embh @ w1t^T ------
__global__ __launch_bounds__(64) void k_gemm(const unsigned short* __restrict__ embh,
                                             const unsigned short* __restrict__ w1t,
                                             float* __restrict__ abm) {
    int wid = blockIdx.x;                 // 512 waves
    int m0 = (wid >> 4) * 32;             // 0..992
    int n0 = (wid & 15) * 32;             // 0..480
    int lane = threadIdx.x;
    int r = lane & 15, g = lane >> 4;
    const short8* Ap0 = (const short8*)(embh + (size_t)(m0 + r) * 768 + g * 8);
    const short8* Ap1 = (const short8*)(embh + (size_t)(m0 + 16 + r) * 768 + g * 8);
    const short8* Bp0 = (const short8*)(w1t + (size_t)(n0 + r) * 768 + g * 8);
    const short8* Bp1 = (const short8*)(w1t + (size_t)(n0 + 16 + r) * 768 + g * 8);
    floatx4 acc00 = {0.f, 0.f, 0.f, 0.f}, acc01 = {0.f, 0.f, 0.f, 0.f};
    floatx4 acc10 = {0.f, 0.f, 0.f, 0.f}, acc11 = {0.f, 0.f, 0.f, 0.f};
#pragma unroll 4
    for (int ks = 0; ks < 768; ks += 32) {
        short8 a0 = Ap0[ks >> 3];
        short8 a1 = Ap1[ks >> 3];
        short8 b0 = Bp0[ks >> 3];
        short8 b1 = Bp1[ks >> 3];
        acc00 = __builtin_amdgcn_mfma_f32_16x16x32_bf16(a0, b0, acc00, 0, 0, 0);
        acc01 = __builtin_amdgcn_mfma_f32_16x16x32_bf16(a0, b1, acc01, 0, 0, 0);
        acc10 = __builtin_amdgcn_mfma_f32_16x16x32_bf16(a1, b0, acc10, 0, 0, 0);
        acc11 = __builtin_amdgcn_mfma_f32_16x16x32_bf16(a1, b1, acc11, 0, 0, 0);
    }
    // C/D layout: col = lane&15, row = (lane>>4)*4 + reg  [m91-verified]
#pragma unroll
    for (int t = 0; t < 4; ++t) {
        int row = g * 4 + t;
        abm[(size_t)(m0 + row) * 512 + n0 + r]           = acc00[t];
        abm[(size_t)(m0 + row) * 512 + n0 + 16 + r]      = acc01[t];
        abm[(size_t)(m0 + 16 + row) * 512 + n0 + r]      = acc10[t];
        abm[(size_t)(m0 + 16 + row) * 512 + n0 + 16 + r] = acc11[t];
    }
}

// ---------------- K8: fused LN+GELU+proj over [B,L,L,L] — fp32 output ----------
__global__ __launch_bounds__(256) void k_hidden(const float* __restrict__ abm,
                                                const float* __restrict__ masks,
                                                const float* __restrict__ bl1,
                                                const float* __restrict__ g1,
                                                const float* __restrict__ b1,
                                                const float* __restrict__ Wc,
                                                const float* __restrict__ bc,
                                                const float* __restrict__ Wc1,
                                                const float* __restrict__ bc1,
                                                float* __restrict__ out) {
    __shared__ __align__(16) float As[32][260];
    __shared__ __align__(16) float Bs[16][260];
    __shared__ __align__(16) float g1s[256];
    __shared__ __align__(16) float b1s[256];
    __shared__ __align__(16) unsigned short wch[256][8];   // bf16-packed proj weights
    __shared__ float bcs[8];
    int tid = threadIdx.x;
    int jt = blockIdx.x, it = blockIdx.y, b = blockIdx.z;
    const float* Ag = abm + (size_t)(b * 256 + it * 32) * 512;
    const float* Bg = abm + (size_t)(b * 256 + jt * 16) * 512 + 256;
#pragma unroll
    for (int u = 0; u < 32; ++u) {
        As[u][tid] = Ag[u * 512 + tid];
    }
#pragma unroll
    for (int u = 0; u < 16; ++u) {
        Bs[u][tid] = Bg[u * 512 + tid] + bl1[tid];
    }
    g1s[tid] = g1[tid];
    b1s[tid] = b1[tid];
    {
        int k = tid;
#pragma unroll
        for (int c = 0; c < 6; ++c) wch[k][c] = f2bf(Wc[k * 6 + c]);
        wch[k][6] = f2bf(Wc1[k * 2]);
        wch[k][7] = f2bf(Wc1[k * 2 + 1]);
    }
    if (tid < 6) bcs[tid] = bc[tid];
    else if (tid < 8) bcs[tid] = bc1[tid - 6];
    __syncthreads();

    int i0 = (tid >> 4) * 2;
    int jl = tid & 15;
    const float4* Ar0 = (const float4*)As[i0];
    const float4* Ar1 = (const float4*)As[i0 + 1];
    const float4* Br  = (const float4*)Bs[jl];
    const float4* G4  = (const float4*)g1s;
    const float4* Bb4 = (const float4*)b1s;
    const uint4*  W4  = (const uint4*)wch;

    // pass 1: mean/var for both rows
    float s0 = 0.f, q0 = 0.f, s1 = 0.f, q1 = 0.f;
#pragma unroll 8
    for (int kq = 0; kq < 64; ++kq) {
        float4 a0 = Ar0[kq], a1 = Ar1[kq], bv = Br[kq];
        float h;
        h = a0.x + bv.x; s0 += h; q0 = fmaf(h, h, q0);
        h = a0.y + bv.y; s0 += h; q0 = fmaf(h, h, q0);
        h = a0.z + bv.z; s0 += h; q0 = fmaf(h, h, q0);
        h = a0.w + bv.w; s0 += h; q0 = fmaf(h, h, q0);
        h = a1.x + bv.x; s1 += h; q1 = fmaf(h, h, q1);
        h = a1.y + bv.y; s1 += h; q1 = fmaf(h, h, q1);
        h = a1.z + bv.z; s1 += h; q1 = fmaf(h, h, q1);
        h = a1.w + bv.w; s1 += h; q1 = fmaf(h, h, q1);
    }
    const float inv256 = 1.f / 256.f;
    float mn0 = s0 * inv256, mn1 = s1 * inv256;
    float r0 = rsqrtf(q0 * inv256 - mn0 * mn0 + 1e-5f);
    float r1 = rsqrtf(q1 * inv256 - mn1 * mn1 + 1e-5f);
    float c0 = -mn0 * r0, c1 = -mn1 * r1;

    float acc0[8], acc1[8];
#pragma unroll
    for (int c = 0; c < 8; ++c) { acc0[c] = 0.f; acc1[c] = 0.f; }

    // GELU(x) ~= x * sigmoid(x*(1.5957691 + 0.0713548*x^2))   (tanh-form)
    const float K1 = -1.5957691216f, K2 = -0.0713548163f;

#define STEP(AE0, AE1, BE, GE, BBE, WIDX) do {                                   \
        float h0 = (AE0) + (BE);                                                 \
        float x0 = fmaf(h0, r0, c0); x0 = fmaf(x0, (GE), (BBE));                 \
        float m0_ = fmaf(x0 * x0, K2, K1);                                       \
        float e0 = __expf(x0 * m0_);                                             \
        float y0 = x0 * __builtin_amdgcn_rcpf(1.f + e0);                         \
        float h1 = (AE1) + (BE);                                                 \
        float x1 = fmaf(h1, r1, c1); x1 = fmaf(x1, (GE), (BBE));                 \
        float m1_ = fmaf(x1 * x1, K2, K1);                                       \
        float e1 = __expf(x1 * m1_);                                             \
        float y1 = x1 * __builtin_amdgcn_rcpf(1.f + e1);                         \
        uint4 wv = W4[WIDX];                                                     \
        float w_0 = blo(wv.x), w_1 = bhi(wv.x), w_2 = blo(wv.y), w_3 = bhi(wv.y);\
        float w_4 = blo(wv.z), w_5 = bhi(wv.z), w_6 = blo(wv.w), w_7 = bhi(wv.w);\
        acc0[0] = fmaf(y0, w_0, acc0[0]); acc1[0] = fmaf(y1, w_0, acc1[0]);      \
        acc0[1] = fmaf(y0, w_1, acc0[1]); acc1[1] = fmaf(y1, w_1, acc1[1]);      \
        acc0[2] = fmaf(y0, w_2, acc0[2]); acc1[2] = fmaf(y1, w_2, acc1[2]);      \
        acc0[3] = fmaf(y0, w_3, acc0[3]); acc1[3] = fmaf(y1, w_3, acc1[3]);      \
        acc0[4] = fmaf(y0, w_4, acc0[4]); acc1[4] = fmaf(y1, w_4, acc1[4]);      \
        acc0[5] = fmaf(y0, w_5, acc0[5]); acc1[5] = fmaf(y1, w_5, acc1[5]);      \
        acc0[6] = fmaf(y0, w_6, acc0[6]); acc1[6] = fmaf(y1, w_6, acc1[6]);      \
        acc0[7] = fmaf(y0, w_7, acc0[7]); acc1[7] = fmaf(y1, w_7, acc1[7]);      \
    } while (0)

#pragma unroll 4
    for (int kq = 0; kq < 64; ++kq) {
        float4 a0 = Ar0[kq], a1 = Ar1[kq], bv = Br[kq];
        float4 g4 = G4[kq], bb4 = Bb4[kq];
        STEP(a0.x, a1.x, bv.x, g4.x, bb4.x, 4 * kq + 0);
        STEP(a0.y, a1.y, bv.y, g4.y, bb4.y, 4 * kq + 1);
        STEP(a0.z, a1.z, bv.z, g4.z, bb4.z, 4 * kq + 2);
        STEP(a0.w, a1.w, bv.w, g4.w, bb4.w, 4 * kq + 3);
    }
#undef STEP

    int i = it * 32 + i0;
    int j = jt * 16 + jl;
    float mk0 = masks[(size_t)(b * 256 + i) * 256 + j];
    float mk1 = masks[(size_t)(b * 256 + i + 1) * 256 + j];
    float* dst0 = out + ((size_t)(b * 256 + i) * 256 + j) * 8;
    float* dst1 = out + ((size_t)(b * 256 + i + 1) * 256 + j) * 8;
    float4 oA, oB;
    oA.x = (acc0[0] + bcs[0]) * mk0; oA.y = (acc0[1] + bcs[1]) * mk0;
    oA.z = (acc0[2] + bcs[2]) * mk0; oA.w = (acc0[3] + bcs[3]) * mk0;
    oB.x = (acc0[4] + bcs[4]) * mk0; oB.y = (acc0[5] + bcs[5]) * mk0;
    oB.z = (acc0[6] + bcs[6]) * mk0; oB.w = (acc0[7] + bcs[7]) * mk0;
    *(float4*)(dst0)     = oA;
    *(float4*)(dst0 + 4) = oB;
    oA.x = (acc1[0] + bcs[0]) * mk1; oA.y = (acc1[1] + bcs[1]) * mk1;
    oA.z = (acc1[2] + bcs[2]) * mk1; oA.w = (acc1[3] + bcs[3]) * mk1;
    oB.x = (acc1[4] + bcs[4]) * mk1; oB.y = (acc1[5] + bcs[5]) * mk1;
    oB.z = (acc1[6] + bcs[6]) * mk1; oB.w = (acc1[7] + bcs[7]) * mk1;
    *(float4*)(dst1)     = oA;
    *(float4*)(dst1 + 4) = oB;
}

// ---------------- launch ----------------
extern "C" void kernel_launch(void* const* d_in, const int* in_sizes, int n_in,
                              void* d_out, int out_size, void* d_ws, size_t ws_size,
                              hipStream_t stream) {
    (void)in_sizes; (void)n_in; (void)out_size; (void)ws_size;
    const float* emb_in = (const float*)d_in[0];
    const float* masks  = (const float*)d_in[1];
    const int* ast = (const int*)d_in[2];
    const int* aed = (const int*)d_in[3];
    const int* ost = (const int*)d_in[4];
    const int* oed = (const int*)d_in[5];
    const int* sid = (const int*)d_in[6];
    const float* E    = (const float*)d_in[7];
    const float* Wtp  = (const float*)d_in[8];
    const float* btp  = (const float*)d_in[9];
    const float* Wat  = (const float*)d_in[10];
    const float* bat  = (const float*)d_in[11];
    const float* Wg   = (const float*)d_in[12];
    const float* bg   = (const float*)d_in[13];
    const float* g0   = (const float*)d_in[14];
    const float* b0   = (const float*)d_in[15];
    const float* W1   = (const float*)d_in[16];
    const float* bl1  = (const float*)d_in[17];
    const float* g1   = (const float*)d_in[18];
    const float* b1   = (const float*)d_in[19];
    const float* Wc   = (const float*)d_in[20];
    const float* bc   = (const float*)d_in[21];
    const float* Wc1  = (const float*)d_in[22];
    const float* bc1  = (const float*)d_in[23];
    float* outp = (float*)d_out;

    float* fw = (float*)d_ws;
    float* emb = fw;                                  // 786432
    float* nf  = emb + 786432;                        // 49152
    float* wts = nf + 49152;                          // 1024   @835584
    float* ae  = wts + 1024;                          // 128    @836608
    int*   hasin = (int*)(ae + 128);                  // 64     @836736
    float* hasedge = (float*)(hasin + 64);            // 4      @836800
    float* xv  = fw + 836864;                         // 100352 (64x1568)
    float* agg = fw + 937216;                         // 98304  (64x1536)
    float* raw = fw + 1035520;                        // 49152  (64x768)
    float* abm = fw + 1084672;                        // 524288
    unsigned short* embh = (unsigned short*)(fw + 1608960);  // 786432 bf16
    unsigned short* w1t  = (unsigned short*)(fw + 2002176);  // 393216 bf16

    dim3 gw(24, 16);
    k_w1t<<<gw, 256, 0, stream>>>(W1, w1t);                 // independent of emb
    k_ln0<<<1024, 256, 0, stream>>>(emb_in, g0, b0, emb);
    k_spans<<<64, 256, 0, stream>>>(emb, ast, aed, ost, oed, sid, xv, nf);
    dim3 gs1(24, 2, 4);
    k_skinny<<<gs1, 256, 0, stream>>>(xv, Wtp, btp, nf, 1568, 1539, 416);
    k_graph<<<4, 256, 0, stream>>>(nf, ast, aed, ost, oed, E, Wat, bat, wts, ae, hasin, hasedge);
    k_agg<<<64, 256, 0, stream>>>(nf, wts, ae, E, agg, raw);
    k_skinny<<<gs1, 256, 0, stream>>>(agg, Wg, bg, raw, 1536, 1536, 384);
    k_scatter<<<64, 256, 0, stream>>>(raw, nf, hasin, hasedge, ast, ost, emb);
    k_cvt<<<768, 256, 0, stream>>>(emb, embh);
    k_gemm<<<512, 64, 0, stream>>>(embh, w1t, abm);
    dim3 g6(16, 8, 4);
    k_hidden<<<g6, 256, 0, stream>>>(abm, masks, bl1, g1, b1, Wc, bc, Wc1, bc1, outp);
}